// Round 19
// baseline (134.601 us; speedup 1.0000x reference)
//
#include <hip/hip_runtime.h>
#include <math.h>

typedef _Float16 half8 __attribute__((ext_vector_type(8)));
typedef _Float16 half2t __attribute__((ext_vector_type(2)));
typedef float f32x16 __attribute__((ext_vector_type(16)));

#define L2E 1.4426950408889634f
#define KPLANE (8*4096*64)
#define QPLANE (8*1024*64)
#define VPLANE (8*64*4096)
#define PSZ 4352   // 4096 halfs O-partials + 128 f32 header

// forward twiddles W32[k] = exp(-2*pi*i*k/32), k = 0..15
__device__ constexpr float FW_R[16] = {
  1.0f, 0.98078528040323044f, 0.92387953251128674f, 0.83146961230254524f,
  0.70710678118654757f, 0.55557023301960218f, 0.38268343236508978f, 0.19509032201612825f,
  0.0f, -0.19509032201612825f, -0.38268343236508978f, -0.55557023301960218f,
  -0.70710678118654757f, -0.83146961230254524f, -0.92387953251128674f, -0.98078528040323044f };
__device__ constexpr float FW_I[16] = {
  -0.0f, -0.19509032201612825f, -0.38268343236508978f, -0.55557023301960218f,
  -0.70710678118654757f, -0.83146961230254524f, -0.92387953251128674f, -0.98078528040323044f,
  -1.0f, -0.98078528040323044f, -0.92387953251128674f, -0.83146961230254524f,
  -0.70710678118654757f, -0.55557023301960218f, -0.38268343236508978f, -0.19509032201612825f };

static __device__ __forceinline__ void fft32(float* xr, float* xi) {
  #pragma unroll
  for (int i = 0; i < 32; i++) {
    int j = ((i & 1) << 4) | ((i & 2) << 2) | (i & 4) | ((i >> 2) & 2) | ((i >> 4) & 1);
    if (j > i) {
      float t = xr[i]; xr[i] = xr[j]; xr[j] = t;
      t = xi[i]; xi[i] = xi[j]; xi[j] = t;
    }
  }
  #pragma unroll
  for (int s = 1; s <= 5; s++) {
    const int len = 1 << s, half = len >> 1;
    #pragma unroll
    for (int j0 = 0; j0 < 32; j0 += len) {
      #pragma unroll
      for (int k = 0; k < half; k++) {
        const float wr = FW_R[k << (5 - s)], wi = FW_I[k << (5 - s)];
        const int a = j0 + k, b = a + half;
        float tr = xr[b] * wr - xi[b] * wi;
        float ti = xr[b] * wi + xi[b] * wr;
        xr[b] = xr[a] - tr; xi[b] = xi[a] - ti;
        xr[a] += tr; xi[a] += ti;
      }
    }
  }
}

// ---------------- fused FFT-32 prep (validated round 10) ----------------
__global__ __launch_bounds__(256) void fft2_all(
    const float* __restrict__ q, const float* __restrict__ kv,
    _Float16* __restrict__ KrH, _Float16* __restrict__ KrL,
    _Float16* __restrict__ KiH, _Float16* __restrict__ KiL,
    _Float16* __restrict__ QrH, _Float16* __restrict__ QrL,
    _Float16* __restrict__ QiH, _Float16* __restrict__ QiL,
    _Float16* __restrict__ Vre, _Float16* __restrict__ Vim)
{
  __shared__ float2 G[8 * 1057];
  const int blk = blockIdx.x;
  const int tid = threadIdx.x;
  const int tr = tid >> 5, col = tid & 31;
  int mode, idx;
  if (blk < 64)       { mode = 0; idx = blk; }
  else if (blk < 320) { mode = 1; idx = blk - 64; }
  else                { mode = 2; idx = blk - 320; }
  int co, r, b;
  if (mode == 0) { co = idx & 7; r = 0;              b = idx >> 3; }
  else           { co = idx & 7; r = (idx >> 3) & 3; b = idx >> 5; }
  const int c = co * 8 + tr;
  const float* src;
  int src_off;
  float scale;
  if (mode == 0)      { src = q;  src_off = (b * 64 + c) * 1024;                  scale = 0.35355339059327373f * L2E; }
  else if (mode == 1) { src = kv; src_off = (b * 128 + c) * 4096 + r * 1024;      scale = 0.35355339059327373f; }
  else                { src = kv; src_off = (b * 128 + 64 + c) * 4096 + r * 1024; scale = 1.0f / 1024.0f; }

  float2* Gt = &G[tr * 1057];

  float xr[32], xi[32];
  #pragma unroll
  for (int n1 = 0; n1 < 32; n1++) { xr[n1] = src[src_off + n1 * 32 + col]; xi[n1] = 0.f; }
  fft32(xr, xi);
  #pragma unroll
  for (int u1 = 0; u1 < 32; u1++) Gt[col * 33 + u1] = make_float2(xr[u1], xi[u1]);
  __syncthreads();

  #pragma unroll
  for (int n2 = 0; n2 < 32; n2++) {
    float2 g = Gt[n2 * 33 + col];
    xr[n2] = g.x; xi[n2] = g.y;
  }
  fft32(xr, xi);
  float* yre = xr;
  float* yim = xi;

  const int su1 = (col + 16) & 31;
  if (mode == 2) {
    int o = (b * 64 + c) * 4096 + r * 1024 + su1 * 32;
    half8 hr[4], hi[4];
    #pragma unroll
    for (int g8 = 0; g8 < 4; g8++)
      #pragma unroll
      for (int e = 0; e < 8; e++) {
        int u2 = ((g8 * 8 + e) + 16) & 31;
        hr[g8][e] = (_Float16)(yre[u2] * scale);
        hi[g8][e] = (_Float16)(yim[u2] * scale);
      }
    #pragma unroll
    for (int g8 = 0; g8 < 4; g8++) {
      *(half8*)(Vre + o + g8 * 8) = hr[g8];
      *(half8*)(Vim + o + g8 * 8) = hi[g8];
    }
  } else {
    __syncthreads();
    #pragma unroll
    for (int u2 = 0; u2 < 32; u2++) {
      int su2 = (u2 + 16) & 31;
      Gt[su1 * 33 + su2] = make_float2(yre[u2] * scale, yim[u2] * scale);
    }
    __syncthreads();
    _Float16 *p0, *p1, *p2, *p3;
    int obase;
    if (mode == 0) { p0 = QrH; p1 = QrL; p2 = QiH; p3 = QiL; obase = (b * 1024) * 64 + co * 8; }
    else           { p0 = KrH; p1 = KrL; p2 = KiH; p3 = KiL; obase = (b * 4096 + r * 1024) * 64 + co * 8; }
    #pragma unroll 2
    for (int k = 0; k < 4; k++) {
      int p = tid + k * 256;
      int pl = (p >> 5) * 33 + (p & 31);
      half8 vH, vL, wH, wL;
      #pragma unroll
      for (int t8 = 0; t8 < 8; t8++) {
        float2 yv = G[t8 * 1057 + pl];
        _Float16 rh = (_Float16)yv.x;
        _Float16 ih = (_Float16)yv.y;
        vH[t8] = rh; vL[t8] = (_Float16)(yv.x - (float)rh);
        wH[t8] = ih; wL[t8] = (_Float16)(yv.y - (float)ih);
      }
      int o = obase + p * 64;
      *(half8*)(p0 + o) = vH;
      *(half8*)(p1 + o) = vL;
      *(half8*)(p2 + o) = wH;
      *(half8*)(p3 + o) = wL;
    }
  }
}

// P repack helpers (validated round 6)
static __device__ inline void storeP(unsigned* pb, const float* p, int lh) {
  #pragma unroll
  for (int u = 0; u < 8; u++) {
    int base = ((u & 1) * 2) + ((u >> 1) * 8) + 4 * lh;
    unsigned short h0 = __builtin_bit_cast(unsigned short, (_Float16)p[2 * u]);
    unsigned short h1 = __builtin_bit_cast(unsigned short, (_Float16)p[2 * u + 1]);
    pb[base >> 1] = (unsigned)h0 | ((unsigned)h1 << 16);
  }
}
static __device__ inline half8 loadP(const unsigned* rp) {
  union { uint4 u; half8 h; } U;
  U.u = *(const uint4*)rp;
  return U.h;
}

// ---------------- MFMA flash attention, s-split 2, 2 blocks/CU ----------------
// grid 512 = 8b x 32 t-tiles x 2 s-halves; 8 warps x 256 s each (8 iters).
// R18 body (VGPR 124, LDS 75.8KB <= 80KB) + R7/R8-validated partial+combine.
__global__ __launch_bounds__(512, 2) void attn_mfma(
    const _Float16* __restrict__ KrH, const _Float16* __restrict__ KrL,
    const _Float16* __restrict__ KiH, const _Float16* __restrict__ KiL,
    const _Float16* __restrict__ QrH, const _Float16* __restrict__ QrL,
    const _Float16* __restrict__ QiH, const _Float16* __restrict__ QiL,
    const _Float16* __restrict__ Vre, const _Float16* __restrict__ Vim,
    _Float16* __restrict__ part)
{
  __shared__ __align__(16) _Float16 qlds[4][4][64][8];
  __shared__ __align__(16) unsigned pbuf[8][32][20];
  __shared__ float mlb[8][32][5];
  __shared__ float obuf[8][32][33];

  const int tid = threadIdx.x;
  const int lane = tid & 63;
  const int warp = tid >> 6;
  const int b = blockIdx.x & 7;
  const int tt = (blockIdx.x >> 3) & 31;
  const int t0 = tt << 5;
  const int shalf = blockIdx.x >> 8;
  const int s0 = shalf << 11;
  const int lm = lane & 31, lh = lane >> 5;

  {
    const _Float16* qp[4] = {QrH, QrL, QiH, QiL};
    #pragma unroll
    for (int jj = 0; jj < 2; jj++) {
      int idx = tid + jj * 512;
      int pl = idx >> 8, ks = (idx >> 6) & 3, ln = idx & 63;
      int t = ln & 31, hh = ln >> 5;
      const _Float16* s = qp[pl] + ((b * 1024 + t0 + t) * 64 + ks * 16 + hh * 8);
      *(half8*)&qlds[pl][ks][ln][0] = *(const half8*)s;
    }
  }
  __syncthreads();

  int kbase = (b * 4096 + s0 + warp * 256 + lm) * 64 + lh * 8;
  const int vbase0 = (b * 64 + lm) * 4096 + s0 + warp * 256 + lh * 8;
  const int vbase1 = vbase0 + 32 * 4096;

  float m_r = -3e38f, m_i = -3e38f, l_r = 0.f, l_i = 0.f;
  f32x16 Or0 = (f32x16)(0.0f), Or1 = (f32x16)(0.0f);
  f32x16 Oi0 = (f32x16)(0.0f), Oi1 = (f32x16)(0.0f);

  #pragma unroll 1
  for (int it = 0; it < 8; ++it) {
    f32x16 A1 = (f32x16)(0.0f), A2 = (f32x16)(0.0f), SI = (f32x16)(0.0f);
    #pragma unroll
    for (int ks = 0; ks < 4; ks++) {
      half8 qrh = *(const half8*)&qlds[0][ks][lane][0];
      half8 qrl = *(const half8*)&qlds[1][ks][lane][0];
      half8 qih = *(const half8*)&qlds[2][ks][lane][0];
      half8 qil = *(const half8*)&qlds[3][ks][lane][0];
      const int ko = kbase + ks * 16;
      half8 krh = *(const half8*)(KrH + ko);
      half8 krl = *(const half8*)(KrL + ko);
      half8 kih = *(const half8*)(KiH + ko);
      half8 kil = *(const half8*)(KiL + ko);
      A1 = __builtin_amdgcn_mfma_f32_32x32x16_f16(krh, qrh, A1, 0, 0, 0);
      A2 = __builtin_amdgcn_mfma_f32_32x32x16_f16(kih, qih, A2, 0, 0, 0);
      SI = __builtin_amdgcn_mfma_f32_32x32x16_f16(kih, qrh, SI, 0, 0, 0);
      A1 = __builtin_amdgcn_mfma_f32_32x32x16_f16(krh, qrl, A1, 0, 0, 0);
      A2 = __builtin_amdgcn_mfma_f32_32x32x16_f16(kih, qil, A2, 0, 0, 0);
      SI = __builtin_amdgcn_mfma_f32_32x32x16_f16(krh, qih, SI, 0, 0, 0);
      A1 = __builtin_amdgcn_mfma_f32_32x32x16_f16(krl, qrh, A1, 0, 0, 0);
      A2 = __builtin_amdgcn_mfma_f32_32x32x16_f16(kil, qih, A2, 0, 0, 0);
      SI = __builtin_amdgcn_mfma_f32_32x32x16_f16(kil, qrh, SI, 0, 0, 0);
      SI = __builtin_amdgcn_mfma_f32_32x32x16_f16(kih, qrl, SI, 0, 0, 0);
      SI = __builtin_amdgcn_mfma_f32_32x32x16_f16(krl, qih, SI, 0, 0, 0);
      SI = __builtin_amdgcn_mfma_f32_32x32x16_f16(krh, qil, SI, 0, 0, 0);
    }

    float sre[16], sim[16];
    #pragma unroll
    for (int rr = 0; rr < 16; rr++) { sre[rr] = A1[rr] - A2[rr]; sim[rr] = SI[rr]; }

    float mtr = sre[0], mti = sim[0];
    #pragma unroll
    for (int rr = 1; rr < 16; rr++) { mtr = fmaxf(mtr, sre[rr]); mti = fmaxf(mti, sim[rr]); }
    mtr = fmaxf(mtr, __shfl_xor(mtr, 32));
    mti = fmaxf(mti, __shfl_xor(mti, 32));

    float pr[16], pi[16];
    {
      float mn = fmaxf(m_r, mtr);
      if (__ballot(mtr > m_r + 11.5f)) {
        float al = exp2f(m_r - mn);
        l_r *= al; m_r = mn;
        #pragma unroll
        for (int rr = 0; rr < 16; rr++) { Or0[rr] *= al; Or1[rr] *= al; }
      }
      float sm = 0.f;
      #pragma unroll
      for (int rr = 0; rr < 16; rr++) { pr[rr] = exp2f(sre[rr] - m_r); sm += pr[rr]; }
      l_r += sm + __shfl_xor(sm, 32);
    }
    {
      float mn = fmaxf(m_i, mti);
      if (__ballot(mti > m_i + 11.5f)) {
        float al = exp2f(m_i - mn);
        l_i *= al; m_i = mn;
        #pragma unroll
        for (int rr = 0; rr < 16; rr++) { Oi0[rr] *= al; Oi1[rr] *= al; }
      }
      float sm = 0.f;
      #pragma unroll
      for (int rr = 0; rr < 16; rr++) { pi[rr] = exp2f(sim[rr] - m_i); sm += pi[rr]; }
      l_i += sm + __shfl_xor(sm, 32);
    }

    // phase RE
    storeP(&pbuf[warp][lm][0], pr, lh);
    #pragma unroll
    for (int h = 0; h < 2; h++) {
      half8 pfr = loadP(&pbuf[warp][lm][h * 8 + 4 * lh]);
      const int vo = it * 32 + h * 16;
      half8 v0r = *(const half8*)(Vre + vbase0 + vo);
      half8 v1r = *(const half8*)(Vre + vbase1 + vo);
      Or0 = __builtin_amdgcn_mfma_f32_32x32x16_f16(v0r, pfr, Or0, 0, 0, 0);
      Or1 = __builtin_amdgcn_mfma_f32_32x32x16_f16(v1r, pfr, Or1, 0, 0, 0);
    }
    // phase IM
    storeP(&pbuf[warp][lm][0], pi, lh);
    #pragma unroll
    for (int h = 0; h < 2; h++) {
      half8 pfi = loadP(&pbuf[warp][lm][h * 8 + 4 * lh]);
      const int vo = it * 32 + h * 16;
      half8 v0i = *(const half8*)(Vim + vbase0 + vo);
      half8 v1i = *(const half8*)(Vim + vbase1 + vo);
      Oi0 = __builtin_amdgcn_mfma_f32_32x32x16_f16(v0i, pfi, Oi0, 0, 0, 0);
      Oi1 = __builtin_amdgcn_mfma_f32_32x32x16_f16(v1i, pfi, Oi1, 0, 0, 0);
    }
    kbase += 32 * 64;
  }

  // ---- tail: merge 8 warps, write normalized fp16 partial + header ----
  if (lane < 32) {
    mlb[warp][lane][0] = m_r; mlb[warp][lane][1] = l_r;
    mlb[warp][lane][2] = m_i; mlb[warp][lane][3] = l_i;
  }
  __syncthreads();
  float Mr = -3e38f, Mi = -3e38f;
  #pragma unroll
  for (int w = 0; w < 8; w++) {
    Mr = fmaxf(Mr, mlb[w][lm][0]);
    Mi = fmaxf(Mi, mlb[w][lm][2]);
  }
  float Lr = 0.f, Li = 0.f;
  #pragma unroll
  for (int w = 0; w < 8; w++) {
    Lr += mlb[w][lm][1] * exp2f(mlb[w][lm][0] - Mr);
    Li += mlb[w][lm][3] * exp2f(mlb[w][lm][2] - Mi);
  }
  const float fr = exp2f(m_r - Mr) / Lr;
  const float fi = exp2f(m_i - Mi) / Li;

  const int pidx = (b * 32 + tt) * 2 + shalf;
  _Float16* pO = part + pidx * PSZ;
  float* pH = (float*)(pO + 4096);

  #pragma unroll 1
  for (int pass = 0; pass < 4; pass++) {
    __syncthreads();
    #pragma unroll
    for (int rr = 0; rr < 16; rr++) {
      int cl = (rr & 3) + 8 * (rr >> 2) + 4 * lh;
      float v = (pass == 0) ? Or0[rr] * fr : (pass == 1) ? Or1[rr] * fr
              : (pass == 2) ? Oi0[rr] * fi : Oi1[rr] * fi;
      obuf[warp][cl][lm] = v;
    }
    __syncthreads();
    {
      int cc = tid >> 4, t2 = (tid & 15) * 2;
      float a0 = 0.f, a1 = 0.f;
      #pragma unroll
      for (int w = 0; w < 8; w++) { a0 += obuf[w][cc][t2]; a1 += obuf[w][cc][t2 + 1]; }
      int ofs = ((pass & 1) ? (32 + cc) : cc) * 32 + ((pass >> 1) ? 2048 : 0);
      half2t hv; hv[0] = (_Float16)a0; hv[1] = (_Float16)a1;
      *(half2t*)&pO[ofs + t2] = hv;
    }
  }
  if (warp == 0 && lane < 32) {
    pH[lane] = Mr; pH[32 + lane] = Lr; pH[64 + lane] = Mi; pH[96 + lane] = Li;
  }
}

// ---------------- combine the 2 s-halves (validated round 8) ----------------
__global__ __launch_bounds__(256) void combine(
    const _Float16* __restrict__ part, float* __restrict__ out)
{
  const int bt = blockIdx.x;          // b*32 + tt
  const int b = bt >> 5, tt = bt & 31;
  const _Float16* p0 = part + (bt * 2) * PSZ;
  const _Float16* p1 = p0 + PSZ;
  const float* h0 = (const float*)(p0 + 4096);
  const float* h1 = (const float*)(p1 + 4096);
  __shared__ float wr0[32], wr1[32], wi0[32], wi1[32];
  const int tid = threadIdx.x;
  if (tid < 32) {
    float m0 = h0[tid], m1 = h1[tid];
    float M = fmaxf(m0, m1);
    float g0 = exp2f(m0 - M) * h0[32 + tid], g1 = exp2f(m1 - M) * h1[32 + tid];
    float iW = 1.f / (g0 + g1);
    wr0[tid] = g0 * iW; wr1[tid] = g1 * iW;
    m0 = h0[64 + tid]; m1 = h1[64 + tid];
    M = fmaxf(m0, m1);
    g0 = exp2f(m0 - M) * h0[96 + tid]; g1 = exp2f(m1 - M) * h1[96 + tid];
    iW = 1.f / (g0 + g1);
    wi0[tid] = g0 * iW; wi1[tid] = g1 * iW;
  }
  __syncthreads();
  const int c = tid >> 2, tg = (tid & 3) * 8;
  const int ob = (b * 64 + c) * 1024 + tt * 32 + tg;
  float o[8];
  #pragma unroll
  for (int k = 0; k < 8; k++) {
    int t = tg + k;
    int e = c * 32 + t;
    o[k] = (float)p0[e] * wr0[t] + (float)p1[e] * wr1[t]
         + (float)p0[2048 + e] * wi0[t] + (float)p1[2048 + e] * wi1[t];
  }
  #pragma unroll
  for (int k = 0; k < 8; k += 4)
    *(float4*)&out[ob + k] = make_float4(o[k], o[k + 1], o[k + 2], o[k + 3]);
}

extern "C" void kernel_launch(void* const* d_in, const int* in_sizes, int n_in,
                              void* d_out, int out_size, void* d_ws, size_t ws_size,
                              hipStream_t stream) {
  const float* q  = (const float*)d_in[0];
  const float* kv = (const float*)d_in[1];
  _Float16* base = (_Float16*)d_ws;
  _Float16* KrH = base;
  _Float16* KrL = KrH + KPLANE;
  _Float16* KiH = KrL + KPLANE;
  _Float16* KiL = KiH + KPLANE;
  _Float16* QrH = KiL + KPLANE;
  _Float16* QrL = QrH + QPLANE;
  _Float16* QiH = QrL + QPLANE;
  _Float16* QiL = QiH + QPLANE;
  _Float16* Vre = QiL + QPLANE;
  _Float16* Vim = Vre + VPLANE;
  _Float16* part = Vim + VPLANE;   // 512 * 4352 halfs = 4.45 MB
  float* out = (float*)d_out;

  fft2_all<<<576, 256, 0, stream>>>(q, kv, KrH, KrL, KiH, KiL,
                                    QrH, QrL, QiH, QiL, Vre, Vim);
  attn_mfma<<<512, 512, 0, stream>>>(KrH, KrL, KiH, KiL,
                                     QrH, QrL, QiH, QiL, Vre, Vim, part);
  combine<<<256, 256, 0, stream>>>(part, out);
}

// Round 20
// 121.480 us; speedup vs baseline: 1.1080x; 1.1080x over previous
//
#include <hip/hip_runtime.h>
#include <math.h>

typedef _Float16 half8 __attribute__((ext_vector_type(8)));
typedef float f32x16 __attribute__((ext_vector_type(16)));

#define L2E 1.4426950408889634f
#define KPLANE (8*4096*64)
#define QPLANE (8*1024*64)
#define VPLANE (8*64*4096)

// forward twiddles W32[k] = exp(-2*pi*i*k/32), k = 0..15
__device__ constexpr float FW_R[16] = {
  1.0f, 0.98078528040323044f, 0.92387953251128674f, 0.83146961230254524f,
  0.70710678118654757f, 0.55557023301960218f, 0.38268343236508978f, 0.19509032201612825f,
  0.0f, -0.19509032201612825f, -0.38268343236508978f, -0.55557023301960218f,
  -0.70710678118654757f, -0.83146961230254524f, -0.92387953251128674f, -0.98078528040323044f };
__device__ constexpr float FW_I[16] = {
  -0.0f, -0.19509032201612825f, -0.38268343236508978f, -0.55557023301960218f,
  -0.70710678118654757f, -0.83146961230254524f, -0.92387953251128674f, -0.98078528040323044f,
  -1.0f, -0.98078528040323044f, -0.92387953251128674f, -0.83146961230254524f,
  -0.70710678118654757f, -0.55557023301960218f, -0.38268343236508978f, -0.19509032201612825f };

static __device__ __forceinline__ void fft32(float* xr, float* xi) {
  #pragma unroll
  for (int i = 0; i < 32; i++) {
    int j = ((i & 1) << 4) | ((i & 2) << 2) | (i & 4) | ((i >> 2) & 2) | ((i >> 4) & 1);
    if (j > i) {
      float t = xr[i]; xr[i] = xr[j]; xr[j] = t;
      t = xi[i]; xi[i] = xi[j]; xi[j] = t;
    }
  }
  #pragma unroll
  for (int s = 1; s <= 5; s++) {
    const int len = 1 << s, half = len >> 1;
    #pragma unroll
    for (int j0 = 0; j0 < 32; j0 += len) {
      #pragma unroll
      for (int k = 0; k < half; k++) {
        const float wr = FW_R[k << (5 - s)], wi = FW_I[k << (5 - s)];
        const int a = j0 + k, b = a + half;
        float tr = xr[b] * wr - xi[b] * wi;
        float ti = xr[b] * wi + xi[b] * wr;
        xr[b] = xr[a] - tr; xi[b] = xi[a] - ti;
        xr[a] += tr; xi[a] += ti;
      }
    }
  }
}

// ---------------- fused FFT-32 prep (validated round 10) ----------------
__global__ __launch_bounds__(256) void fft2_all(
    const float* __restrict__ q, const float* __restrict__ kv,
    _Float16* __restrict__ KrH, _Float16* __restrict__ KrL,
    _Float16* __restrict__ KiH, _Float16* __restrict__ KiL,
    _Float16* __restrict__ QrH, _Float16* __restrict__ QrL,
    _Float16* __restrict__ QiH, _Float16* __restrict__ QiL,
    _Float16* __restrict__ Vre, _Float16* __restrict__ Vim)
{
  __shared__ float2 G[8 * 1057];
  const int blk = blockIdx.x;
  const int tid = threadIdx.x;
  const int tr = tid >> 5, col = tid & 31;
  int mode, idx;
  if (blk < 64)       { mode = 0; idx = blk; }
  else if (blk < 320) { mode = 1; idx = blk - 64; }
  else                { mode = 2; idx = blk - 320; }
  int co, r, b;
  if (mode == 0) { co = idx & 7; r = 0;              b = idx >> 3; }
  else           { co = idx & 7; r = (idx >> 3) & 3; b = idx >> 5; }
  const int c = co * 8 + tr;
  const float* src;
  int src_off;
  float scale;
  if (mode == 0)      { src = q;  src_off = (b * 64 + c) * 1024;                  scale = 0.35355339059327373f * L2E; }
  else if (mode == 1) { src = kv; src_off = (b * 128 + c) * 4096 + r * 1024;      scale = 0.35355339059327373f; }
  else                { src = kv; src_off = (b * 128 + 64 + c) * 4096 + r * 1024; scale = 1.0f / 1024.0f; }

  float2* Gt = &G[tr * 1057];

  float xr[32], xi[32];
  #pragma unroll
  for (int n1 = 0; n1 < 32; n1++) { xr[n1] = src[src_off + n1 * 32 + col]; xi[n1] = 0.f; }
  fft32(xr, xi);
  #pragma unroll
  for (int u1 = 0; u1 < 32; u1++) Gt[col * 33 + u1] = make_float2(xr[u1], xi[u1]);
  __syncthreads();

  #pragma unroll
  for (int n2 = 0; n2 < 32; n2++) {
    float2 g = Gt[n2 * 33 + col];
    xr[n2] = g.x; xi[n2] = g.y;
  }
  fft32(xr, xi);
  float* yre = xr;
  float* yim = xi;

  const int su1 = (col + 16) & 31;
  if (mode == 2) {
    int o = (b * 64 + c) * 4096 + r * 1024 + su1 * 32;
    half8 hr[4], hi[4];
    #pragma unroll
    for (int g8 = 0; g8 < 4; g8++)
      #pragma unroll
      for (int e = 0; e < 8; e++) {
        int u2 = ((g8 * 8 + e) + 16) & 31;
        hr[g8][e] = (_Float16)(yre[u2] * scale);
        hi[g8][e] = (_Float16)(yim[u2] * scale);
      }
    #pragma unroll
    for (int g8 = 0; g8 < 4; g8++) {
      *(half8*)(Vre + o + g8 * 8) = hr[g8];
      *(half8*)(Vim + o + g8 * 8) = hi[g8];
    }
  } else {
    __syncthreads();
    #pragma unroll
    for (int u2 = 0; u2 < 32; u2++) {
      int su2 = (u2 + 16) & 31;
      Gt[su1 * 33 + su2] = make_float2(yre[u2] * scale, yim[u2] * scale);
    }
    __syncthreads();
    _Float16 *p0, *p1, *p2, *p3;
    int obase;
    if (mode == 0) { p0 = QrH; p1 = QrL; p2 = QiH; p3 = QiL; obase = (b * 1024) * 64 + co * 8; }
    else           { p0 = KrH; p1 = KrL; p2 = KiH; p3 = KiL; obase = (b * 4096 + r * 1024) * 64 + co * 8; }
    #pragma unroll 2
    for (int k = 0; k < 4; k++) {
      int p = tid + k * 256;
      int pl = (p >> 5) * 33 + (p & 31);
      half8 vH, vL, wH, wL;
      #pragma unroll
      for (int t8 = 0; t8 < 8; t8++) {
        float2 yv = G[t8 * 1057 + pl];
        _Float16 rh = (_Float16)yv.x;
        _Float16 ih = (_Float16)yv.y;
        vH[t8] = rh; vL[t8] = (_Float16)(yv.x - (float)rh);
        wH[t8] = ih; wL[t8] = (_Float16)(yv.y - (float)ih);
      }
      int o = obase + p * 64;
      *(half8*)(p0 + o) = vH;
      *(half8*)(p1 + o) = vL;
      *(half8*)(p2 + o) = wH;
      *(half8*)(p3 + o) = wL;
    }
  }
}

// P repack helpers (validated round 6)
static __device__ inline void storeP(unsigned* pb, const float* p, int lh) {
  #pragma unroll
  for (int u = 0; u < 8; u++) {
    int base = ((u & 1) * 2) + ((u >> 1) * 8) + 4 * lh;
    unsigned short h0 = __builtin_bit_cast(unsigned short, (_Float16)p[2 * u]);
    unsigned short h1 = __builtin_bit_cast(unsigned short, (_Float16)p[2 * u + 1]);
    pb[base >> 1] = (unsigned)h0 | ((unsigned)h1 << 16);
  }
}
static __device__ inline half8 loadP(const unsigned* rp) {
  union { uint4 u; half8 h; } U;
  U.u = *(const uint4*)rp;
  return U.h;
}

// ---------------- MFMA flash attention (best validated config, R18) ----------
// grid 256 = 8b x 32 t-tiles; 8 warps x 512 s each. Single time-shared P
// buffer (re phase then im phase; same-wave LDS write->read). VGPR 124,
// LDS 75.8KB, 2 waves/SIMD — structural ceiling of this state size.
__global__ __launch_bounds__(512, 2) void attn_mfma(
    const _Float16* __restrict__ KrH, const _Float16* __restrict__ KrL,
    const _Float16* __restrict__ KiH, const _Float16* __restrict__ KiL,
    const _Float16* __restrict__ QrH, const _Float16* __restrict__ QrL,
    const _Float16* __restrict__ QiH, const _Float16* __restrict__ QiL,
    const _Float16* __restrict__ Vre, const _Float16* __restrict__ Vim,
    float* __restrict__ out)
{
  __shared__ __align__(16) _Float16 qlds[4][4][64][8];
  __shared__ __align__(16) unsigned pbuf[8][32][20];
  __shared__ float mlb[8][32][5];
  __shared__ float obuf[8][32][33];

  const int tid = threadIdx.x;
  const int lane = tid & 63;
  const int warp = tid >> 6;
  const int b = blockIdx.x & 7;
  const int t0 = (blockIdx.x >> 3) << 5;
  const int lm = lane & 31, lh = lane >> 5;

  {
    const _Float16* qp[4] = {QrH, QrL, QiH, QiL};
    #pragma unroll
    for (int jj = 0; jj < 2; jj++) {
      int idx = tid + jj * 512;
      int pl = idx >> 8, ks = (idx >> 6) & 3, ln = idx & 63;
      int t = ln & 31, hh = ln >> 5;
      const _Float16* s = qp[pl] + ((b * 1024 + t0 + t) * 64 + ks * 16 + hh * 8);
      *(half8*)&qlds[pl][ks][ln][0] = *(const half8*)s;
    }
  }
  __syncthreads();

  int kbase = (b * 4096 + warp * 512 + lm) * 64 + lh * 8;
  const int vbase0 = (b * 64 + lm) * 4096 + warp * 512 + lh * 8;
  const int vbase1 = vbase0 + 32 * 4096;

  float m_r = -3e38f, m_i = -3e38f, l_r = 0.f, l_i = 0.f;
  f32x16 Or0 = (f32x16)(0.0f), Or1 = (f32x16)(0.0f);
  f32x16 Oi0 = (f32x16)(0.0f), Oi1 = (f32x16)(0.0f);

  #pragma unroll 1
  for (int it = 0; it < 16; ++it) {
    f32x16 A1 = (f32x16)(0.0f), A2 = (f32x16)(0.0f), SI = (f32x16)(0.0f);
    #pragma unroll
    for (int ks = 0; ks < 4; ks++) {
      half8 qrh = *(const half8*)&qlds[0][ks][lane][0];
      half8 qrl = *(const half8*)&qlds[1][ks][lane][0];
      half8 qih = *(const half8*)&qlds[2][ks][lane][0];
      half8 qil = *(const half8*)&qlds[3][ks][lane][0];
      const int ko = kbase + ks * 16;
      half8 krh = *(const half8*)(KrH + ko);
      half8 krl = *(const half8*)(KrL + ko);
      half8 kih = *(const half8*)(KiH + ko);
      half8 kil = *(const half8*)(KiL + ko);
      A1 = __builtin_amdgcn_mfma_f32_32x32x16_f16(krh, qrh, A1, 0, 0, 0);
      A2 = __builtin_amdgcn_mfma_f32_32x32x16_f16(kih, qih, A2, 0, 0, 0);
      SI = __builtin_amdgcn_mfma_f32_32x32x16_f16(kih, qrh, SI, 0, 0, 0);
      A1 = __builtin_amdgcn_mfma_f32_32x32x16_f16(krh, qrl, A1, 0, 0, 0);
      A2 = __builtin_amdgcn_mfma_f32_32x32x16_f16(kih, qil, A2, 0, 0, 0);
      SI = __builtin_amdgcn_mfma_f32_32x32x16_f16(krh, qih, SI, 0, 0, 0);
      A1 = __builtin_amdgcn_mfma_f32_32x32x16_f16(krl, qrh, A1, 0, 0, 0);
      A2 = __builtin_amdgcn_mfma_f32_32x32x16_f16(kil, qih, A2, 0, 0, 0);
      SI = __builtin_amdgcn_mfma_f32_32x32x16_f16(kil, qrh, SI, 0, 0, 0);
      SI = __builtin_amdgcn_mfma_f32_32x32x16_f16(kih, qrl, SI, 0, 0, 0);
      SI = __builtin_amdgcn_mfma_f32_32x32x16_f16(krl, qih, SI, 0, 0, 0);
      SI = __builtin_amdgcn_mfma_f32_32x32x16_f16(krh, qil, SI, 0, 0, 0);
    }

    float sre[16], sim[16];
    #pragma unroll
    for (int rr = 0; rr < 16; rr++) { sre[rr] = A1[rr] - A2[rr]; sim[rr] = SI[rr]; }

    float mtr = sre[0], mti = sim[0];
    #pragma unroll
    for (int rr = 1; rr < 16; rr++) { mtr = fmaxf(mtr, sre[rr]); mti = fmaxf(mti, sim[rr]); }
    mtr = fmaxf(mtr, __shfl_xor(mtr, 32));
    mti = fmaxf(mti, __shfl_xor(mti, 32));

    float pr[16], pi[16];
    {
      float mn = fmaxf(m_r, mtr);
      if (__ballot(mtr > m_r + 11.5f)) {
        float al = exp2f(m_r - mn);
        l_r *= al; m_r = mn;
        #pragma unroll
        for (int rr = 0; rr < 16; rr++) { Or0[rr] *= al; Or1[rr] *= al; }
      }
      float sm = 0.f;
      #pragma unroll
      for (int rr = 0; rr < 16; rr++) { pr[rr] = exp2f(sre[rr] - m_r); sm += pr[rr]; }
      l_r += sm + __shfl_xor(sm, 32);
    }
    {
      float mn = fmaxf(m_i, mti);
      if (__ballot(mti > m_i + 11.5f)) {
        float al = exp2f(m_i - mn);
        l_i *= al; m_i = mn;
        #pragma unroll
        for (int rr = 0; rr < 16; rr++) { Oi0[rr] *= al; Oi1[rr] *= al; }
      }
      float sm = 0.f;
      #pragma unroll
      for (int rr = 0; rr < 16; rr++) { pi[rr] = exp2f(sim[rr] - m_i); sm += pi[rr]; }
      l_i += sm + __shfl_xor(sm, 32);
    }

    // ---- phase RE: repack pr -> PV real MFMAs ----
    storeP(&pbuf[warp][lm][0], pr, lh);
    #pragma unroll
    for (int h = 0; h < 2; h++) {
      half8 pfr = loadP(&pbuf[warp][lm][h * 8 + 4 * lh]);
      const int vo = it * 32 + h * 16;
      half8 v0r = *(const half8*)(Vre + vbase0 + vo);
      half8 v1r = *(const half8*)(Vre + vbase1 + vo);
      Or0 = __builtin_amdgcn_mfma_f32_32x32x16_f16(v0r, pfr, Or0, 0, 0, 0);
      Or1 = __builtin_amdgcn_mfma_f32_32x32x16_f16(v1r, pfr, Or1, 0, 0, 0);
    }
    // ---- phase IM: repack pi over same slots -> PV imag MFMAs ----
    storeP(&pbuf[warp][lm][0], pi, lh);
    #pragma unroll
    for (int h = 0; h < 2; h++) {
      half8 pfi = loadP(&pbuf[warp][lm][h * 8 + 4 * lh]);
      const int vo = it * 32 + h * 16;
      half8 v0i = *(const half8*)(Vim + vbase0 + vo);
      half8 v1i = *(const half8*)(Vim + vbase1 + vo);
      Oi0 = __builtin_amdgcn_mfma_f32_32x32x16_f16(v0i, pfi, Oi0, 0, 0, 0);
      Oi1 = __builtin_amdgcn_mfma_f32_32x32x16_f16(v1i, pfi, Oi1, 0, 0, 0);
    }
    kbase += 32 * 64;
  }

  if (lane < 32) {
    mlb[warp][lane][0] = m_r; mlb[warp][lane][1] = l_r;
    mlb[warp][lane][2] = m_i; mlb[warp][lane][3] = l_i;
  }
  __syncthreads();
  float Mr = -3e38f, Mi = -3e38f;
  #pragma unroll
  for (int w = 0; w < 8; w++) {
    Mr = fmaxf(Mr, mlb[w][lm][0]);
    Mi = fmaxf(Mi, mlb[w][lm][2]);
  }
  float Lr = 0.f, Li = 0.f;
  #pragma unroll
  for (int w = 0; w < 8; w++) {
    Lr += mlb[w][lm][1] * exp2f(mlb[w][lm][0] - Mr);
    Li += mlb[w][lm][3] * exp2f(mlb[w][lm][2] - Mi);
  }
  const float fr = exp2f(m_r - Mr) / Lr;
  const float fi = exp2f(m_i - Mi) / Li;

  #pragma unroll
  for (int rr = 0; rr < 16; rr++) {
    int cl = (rr & 3) + 8 * (rr >> 2) + 4 * lh;
    obuf[warp][cl][lm] = Or0[rr] * fr + Oi0[rr] * fi;
  }
  __syncthreads();
  {
    int c = tid >> 4, t2 = (tid & 15) * 2;
    float2 acc = make_float2(0.f, 0.f);
    #pragma unroll
    for (int w = 0; w < 8; w++) { acc.x += obuf[w][c][t2]; acc.y += obuf[w][c][t2 + 1]; }
    *(float2*)&out[(b * 64 + c) * 1024 + t0 + t2] = acc;
  }
  __syncthreads();
  #pragma unroll
  for (int rr = 0; rr < 16; rr++) {
    int cl = (rr & 3) + 8 * (rr >> 2) + 4 * lh;
    obuf[warp][cl][lm] = Or1[rr] * fr + Oi1[rr] * fi;
  }
  __syncthreads();
  {
    int c = tid >> 4, t2 = (tid & 15) * 2;
    float2 acc = make_float2(0.f, 0.f);
    #pragma unroll
    for (int w = 0; w < 8; w++) { acc.x += obuf[w][c][t2]; acc.y += obuf[w][c][t2 + 1]; }
    *(float2*)&out[(b * 64 + 32 + c) * 1024 + t0 + t2] = acc;
  }
}

extern "C" void kernel_launch(void* const* d_in, const int* in_sizes, int n_in,
                              void* d_out, int out_size, void* d_ws, size_t ws_size,
                              hipStream_t stream) {
  const float* q  = (const float*)d_in[0];
  const float* kv = (const float*)d_in[1];
  _Float16* base = (_Float16*)d_ws;
  _Float16* KrH = base;
  _Float16* KrL = KrH + KPLANE;
  _Float16* KiH = KrL + KPLANE;
  _Float16* KiL = KiH + KPLANE;
  _Float16* QrH = KiL + KPLANE;
  _Float16* QrL = QrH + QPLANE;
  _Float16* QiH = QrL + QPLANE;
  _Float16* QiL = QiH + QPLANE;
  _Float16* Vre = QiL + QPLANE;
  _Float16* Vim = Vre + VPLANE;
  float* out = (float*)d_out;

  fft2_all<<<576, 256, 0, stream>>>(q, kv, KrH, KrL, KiH, KiL,
                                    QrH, QrL, QiH, QiL, Vre, Vim);
  attn_mfma<<<256, 512, 0, stream>>>(KrH, KrL, KiH, KiL,
                                     QrH, QrL, QiH, QiL, Vre, Vim, out);
}